// Round 1
// baseline (712.160 us; speedup 1.0000x reference)
//
#include <hip/hip_runtime.h>
#include <math.h>

typedef __bf16 bf16;
typedef __bf16 bf16x8 __attribute__((ext_vector_type(8)));
typedef __bf16 bf16x4 __attribute__((ext_vector_type(4)));
typedef float  f32x4  __attribute__((ext_vector_type(4)));

#define MFMA(a, b, c) __builtin_amdgcn_mfma_f32_16x16x32_bf16((a), (b), (c), 0, 0, 0)

static constexpr int B_ = 8, C_ = 256, N_ = 4096;
// log2(e) / sqrt(C): folded into q so softmax uses exp2f directly
static constexpr float QSCALE = 0.09016844005556021f;

// workspace layout (bytes)
static constexpr size_t HT_OFF = 0;                    // hT  [B][N][C] bf16 : 16 MB
static constexpr size_t QT_OFF = 16777216;             // qT  [B][N][C] bf16
static constexpr size_t KT_OFF = 33554432;             // kT  [B][N][C] bf16
static constexpr size_t V_OFF  = 50331648;             // v   [B][C][N] bf16
static constexpr size_t WQ_OFF = 67108864;             // weights bf16, 128 KB each
static constexpr size_t WK_OFF = WQ_OFF + 131072;
static constexpr size_t WV_OFF = WK_OFF + 131072;
static constexpr size_t WO_OFF = WV_OFF + 131072;

// ---------------------------------------------------------------- weights fp32->bf16
__global__ __launch_bounds__(256) void wconv_kernel(
    const float* __restrict__ wq, const float* __restrict__ wk,
    const float* __restrict__ wv, const float* __restrict__ wo,
    bf16* __restrict__ oq, bf16* __restrict__ ok, bf16* __restrict__ ov, bf16* __restrict__ oo) {
  int i = blockIdx.x * 256 + threadIdx.x;   // 65536 total
  oq[i] = (bf16)wq[i];
  ok[i] = (bf16)wk[i];
  ov[i] = (bf16)wv[i];
  oo[i] = (bf16)wo[i];
}

// ---------------------------------------------------------------- groupnorm -> hT [B][N][C] bf16
__global__ __launch_bounds__(256) void gn_kernel(
    const float* __restrict__ x, const float* __restrict__ gsc, const float* __restrict__ gbi,
    bf16* __restrict__ hT) {
  int b = blockIdx.x >> 5, g = blockIdx.x & 31, c0 = g * 8;
  int t = threadIdx.x;
  const float* base = x + ((size_t)(b * C_ + c0)) * N_;   // 8 channels * 4096, contiguous
  float s = 0.f, ss = 0.f;
  const f32x4* b4 = (const f32x4*)base;
#pragma unroll
  for (int p = 0; p < 32; p++) {
    f32x4 v = b4[t + p * 256];
    s  += v[0] + v[1] + v[2] + v[3];
    ss += v[0] * v[0] + v[1] * v[1] + v[2] * v[2] + v[3] * v[3];
  }
#pragma unroll
  for (int off = 1; off < 64; off <<= 1) {
    s  += __shfl_xor(s, off);
    ss += __shfl_xor(ss, off);
  }
  __shared__ float red[8];
  if ((t & 63) == 0) { red[(t >> 6) * 2] = s; red[(t >> 6) * 2 + 1] = ss; }
  __syncthreads();
  s  = red[0] + red[2] + red[4] + red[6];
  ss = red[1] + red[3] + red[5] + red[7];
  float mean = s * (1.f / 32768.f);
  float var  = ss * (1.f / 32768.f) - mean * mean;
  float rstd = rsqrtf(var + 1e-6f);
  float aa[8], bb[8];
#pragma unroll
  for (int cc = 0; cc < 8; cc++) {
    aa[cc] = rstd * gsc[c0 + cc];
    bb[cc] = gbi[c0 + cc] - mean * aa[cc];
  }
  for (int ii = 0; ii < 16; ii++) {
    int i = t + ii * 256;
    bf16x8 o;
#pragma unroll
    for (int cc = 0; cc < 8; cc++) o[cc] = (bf16)(base[(size_t)cc * N_ + i] * aa[cc] + bb[cc]);
    *(bf16x8*)(hT + ((size_t)(b * N_ + i)) * C_ + c0) = o;  // 16B packed store
  }
}

// ---------------------------------------------------------------- QKV GEMMs
// qT[i][c] = (sum_c' wq[c][c'] h[c'][i] + bq[c]) * QSCALE   (bf16, [B][N][C])
// kT[i][c] =  sum_c' wk[c][c'] h[c'][i] + bk[c]             (bf16, [B][N][C])
// v [c][i] =  sum_c' wv[c][c'] h[c'][i] + bv[c]             (bf16, [B][C][N])
__global__ __launch_bounds__(256) void qkv_kernel(
    const bf16* __restrict__ hT,
    const bf16* __restrict__ wqb, const bf16* __restrict__ wkb, const bf16* __restrict__ wvb,
    const float* __restrict__ bq, const float* __restrict__ bk, const float* __restrict__ bv,
    bf16* __restrict__ qT, bf16* __restrict__ kT, bf16* __restrict__ vv) {
  int b = blockIdx.x >> 6, i0 = (blockIdx.x & 63) << 6;
  int t = threadIdx.x, w = t >> 6, lane = t & 63, quad = lane >> 4, l15 = lane & 15;
  __shared__ bf16 hl[64 * 264];   // hT tile [64 i][256 c'], pad +8
#pragma unroll
  for (int p = 0; p < 8; p++) {
    int u = t + p * 256, r = u >> 5, c16 = u & 31;
    *(bf16x8*)(hl + r * 264 + c16 * 8) =
        *(const bf16x8*)(hT + ((size_t)(b * N_ + i0 + r)) * C_ + c16 * 8);
  }
  __syncthreads();
  int cw0 = w * 64;

  // ---- Q & K pass: D rows = c_out, cols = i
  f32x4 aq[4][4], ak[4][4];
#pragma unroll
  for (int a = 0; a < 4; a++)
#pragma unroll
    for (int bb2 = 0; bb2 < 4; bb2++) { aq[a][bb2] = (f32x4){0.f,0.f,0.f,0.f}; ak[a][bb2] = (f32x4){0.f,0.f,0.f,0.f}; }
  for (int kc = 0; kc < 8; kc++) {
    bf16x8 hb[4];
#pragma unroll
    for (int it = 0; it < 4; it++)
      hb[it] = *(const bf16x8*)(hl + (it * 16 + l15) * 264 + kc * 32 + quad * 8);
#pragma unroll
    for (int ct = 0; ct < 4; ct++) {
      bf16x8 wqf = *(const bf16x8*)(wqb + ((size_t)(cw0 + ct * 16 + l15)) * C_ + kc * 32 + quad * 8);
      bf16x8 wkf = *(const bf16x8*)(wkb + ((size_t)(cw0 + ct * 16 + l15)) * C_ + kc * 32 + quad * 8);
#pragma unroll
      for (int it = 0; it < 4; it++) {
        aq[ct][it] = MFMA(wqf, hb[it], aq[ct][it]);
        ak[ct][it] = MFMA(wkf, hb[it], ak[ct][it]);
      }
    }
  }
#pragma unroll
  for (int ct = 0; ct < 4; ct++)
#pragma unroll
    for (int it = 0; it < 4; it++) {
      int c4 = cw0 + ct * 16 + quad * 4;           // 4 consecutive c per lane
      int i  = i0 + it * 16 + l15;
      f32x4 bq4 = *(const f32x4*)(bq + c4);
      f32x4 bk4 = *(const f32x4*)(bk + c4);
      bf16x4 qo, ko;
#pragma unroll
      for (int r = 0; r < 4; r++) {
        qo[r] = (bf16)((aq[ct][it][r] + bq4[r]) * QSCALE);
        ko[r] = (bf16)(ak[ct][it][r] + bk4[r]);
      }
      *(bf16x4*)(qT + ((size_t)(b * N_ + i)) * C_ + c4) = qo;   // 8B packed
      *(bf16x4*)(kT + ((size_t)(b * N_ + i)) * C_ + c4) = ko;
    }

  // ---- V pass: D rows = i, cols = c_out
  f32x4 av[4][4];
#pragma unroll
  for (int a = 0; a < 4; a++)
#pragma unroll
    for (int bb2 = 0; bb2 < 4; bb2++) av[a][bb2] = (f32x4){0.f,0.f,0.f,0.f};
  for (int kc = 0; kc < 8; kc++) {
    bf16x8 ha[4];
#pragma unroll
    for (int it = 0; it < 4; it++)
      ha[it] = *(const bf16x8*)(hl + (it * 16 + l15) * 264 + kc * 32 + quad * 8);
#pragma unroll
    for (int ct = 0; ct < 4; ct++) {
      bf16x8 wvf = *(const bf16x8*)(wvb + ((size_t)(cw0 + ct * 16 + l15)) * C_ + kc * 32 + quad * 8);
#pragma unroll
      for (int it = 0; it < 4; it++) av[it][ct] = MFMA(ha[it], wvf, av[it][ct]);
    }
  }
#pragma unroll
  for (int it = 0; it < 4; it++)
#pragma unroll
    for (int ct = 0; ct < 4; ct++) {
      int c  = cw0 + ct * 16 + l15;
      int i4 = i0 + it * 16 + quad * 4;            // 4 consecutive i per lane
      float bvc = bv[c];
      bf16x4 vo;
#pragma unroll
      for (int r = 0; r < 4; r++) vo[r] = (bf16)(av[it][ct][r] + bvc);
      *(bf16x4*)(vv + ((size_t)(b * C_ + c)) * N_ + i4) = vo;   // 8B packed
    }
}

// ---------------------------------------------------------------- flash attention + fused O-proj + skip
__global__ __launch_bounds__(256) void attn_kernel(
    const bf16* __restrict__ qT, const bf16* __restrict__ kT, const bf16* __restrict__ vv,
    const bf16* __restrict__ wob, const float* __restrict__ bo,
    const float* __restrict__ x, float* __restrict__ out) {
  int b = blockIdx.x >> 6, i0 = (blockIdx.x & 63) << 6;
  int t = threadIdx.x, w = t >> 6, lane = t & 63, quad = lane >> 4, l15 = lane & 15;
  // LDS: kT tile [32][264] | v tile [256][40] | P [4 waves][16][40]
  __shared__ bf16 lds[32 * 264 + 256 * 40 + 4 * 16 * 40];
  bf16* kTl = lds;
  bf16* vl  = lds + 32 * 264;
  bf16* pl  = lds + 32 * 264 + 256 * 40 + w * 16 * 40;

  int iw = i0 + w * 16;                 // this wave's 16 query rows
  bf16x8 qf[8];
#pragma unroll
  for (int kc = 0; kc < 8; kc++)
    qf[kc] = *(const bf16x8*)(qT + ((size_t)(b * N_ + iw + l15)) * C_ + kc * 32 + quad * 8);

  f32x4 of[16];
#pragma unroll
  for (int cf = 0; cf < 16; cf++) of[cf] = (f32x4){0.f, 0.f, 0.f, 0.f};
  float m_[4] = {-INFINITY, -INFINITY, -INFINITY, -INFINITY};
  float l_[4] = {0.f, 0.f, 0.f, 0.f};

  for (int jt = 0; jt < 128; jt++) {
    int j0 = jt * 32;
    __syncthreads();                    // protect LDS reuse from previous iter
#pragma unroll
    for (int p = 0; p < 4; p++) {       // stage kT tile: 32 rows x 512B, coalesced
      int u = t + p * 256, r = u >> 5, c16 = u & 31;
      *(bf16x8*)(kTl + r * 264 + c16 * 8) =
          *(const bf16x8*)(kT + ((size_t)(b * N_ + j0 + r)) * C_ + c16 * 8);
    }
#pragma unroll
    for (int p = 0; p < 4; p++) {       // stage v tile: 256 rows x 64B
      int u = t + p * 256, c = u >> 2, pt = u & 3;
      *(bf16x8*)(vl + c * 40 + pt * 8) =
          *(const bf16x8*)(vv + ((size_t)(b * C_ + c)) * N_ + j0 + pt * 8);
    }
    __syncthreads();

    // S = Q^T K  (rows i, cols j0..j0+31), already in exp2 domain
    f32x4 s0 = {0.f, 0.f, 0.f, 0.f}, s1 = {0.f, 0.f, 0.f, 0.f};
#pragma unroll
    for (int kc = 0; kc < 8; kc++) {
      bf16x8 k0 = *(const bf16x8*)(kTl + l15 * 264 + kc * 32 + quad * 8);
      bf16x8 k1 = *(const bf16x8*)(kTl + (16 + l15) * 264 + kc * 32 + quad * 8);
      s0 = MFMA(qf[kc], k0, s0);
      s1 = MFMA(qf[kc], k1, s1);
    }

    // online softmax; row r of this lane = iw + quad*4 + r, cols spread over quad's 16 lanes
    float p0[4], p1[4], al[4];
#pragma unroll
    for (int r = 0; r < 4; r++) {
      float mx = fmaxf(s0[r], s1[r]);
      mx = fmaxf(mx, __shfl_xor(mx, 1));
      mx = fmaxf(mx, __shfl_xor(mx, 2));
      mx = fmaxf(mx, __shfl_xor(mx, 4));
      mx = fmaxf(mx, __shfl_xor(mx, 8));
      float mn = fmaxf(m_[r], mx);
      al[r] = exp2f(m_[r] - mn);
      m_[r] = mn;
      p0[r] = exp2f(s0[r] - mn);
      p1[r] = exp2f(s1[r] - mn);
      float rs = p0[r] + p1[r];
      rs += __shfl_xor(rs, 1);
      rs += __shfl_xor(rs, 2);
      rs += __shfl_xor(rs, 4);
      rs += __shfl_xor(rs, 8);
      l_[r] = l_[r] * al[r] + rs;
    }
#pragma unroll
    for (int cf = 0; cf < 16; cf++)
#pragma unroll
      for (int r = 0; r < 4; r++) of[cf][r] *= al[r];

    // P: C-layout -> A-layout via per-wave LDS round trip (DS ops in-order within a wave)
#pragma unroll
    for (int r = 0; r < 4; r++) {
      pl[(quad * 4 + r) * 40 + l15]      = (bf16)p0[r];
      pl[(quad * 4 + r) * 40 + 16 + l15] = (bf16)p1[r];
    }
    bf16x8 pA = *(const bf16x8*)(pl + l15 * 40 + quad * 8);
#pragma unroll
    for (int cf = 0; cf < 16; cf++) {
      bf16x8 bV = *(const bf16x8*)(vl + (cf * 16 + l15) * 40 + quad * 8);
      of[cf] = MFMA(pA, bV, of[cf]);   // O[i][c] += P[i][j] v[c][j]
    }
  }

  // ---- epilogue: z = O/l -> LDS (zT [64][264]) -> out = x + Wo z + bo
  float inv[4];
#pragma unroll
  for (int r = 0; r < 4; r++) inv[r] = 1.f / l_[r];
  __syncthreads();
  bf16* zl = lds;
#pragma unroll
  for (int cf = 0; cf < 16; cf++)
#pragma unroll
    for (int r = 0; r < 4; r++)
      zl[(w * 16 + quad * 4 + r) * 264 + cf * 16 + l15] = (bf16)(of[cf][r] * inv[r]);
  __syncthreads();

  f32x4 oa[4][4];
#pragma unroll
  for (int a = 0; a < 4; a++)
#pragma unroll
    for (int bb2 = 0; bb2 < 4; bb2++) oa[a][bb2] = (f32x4){0.f, 0.f, 0.f, 0.f};
  for (int kc = 0; kc < 8; kc++) {
    bf16x8 za[4];
#pragma unroll
    for (int it = 0; it < 4; it++)
      za[it] = *(const bf16x8*)(zl + (it * 16 + l15) * 264 + kc * 32 + quad * 8);
#pragma unroll
    for (int ctl = 0; ctl < 4; ctl++) {
      bf16x8 wf = *(const bf16x8*)(wob + ((size_t)(w * 64 + ctl * 16 + l15)) * C_ + kc * 32 + quad * 8);
#pragma unroll
      for (int it = 0; it < 4; it++) oa[ctl][it] = MFMA(za[it], wf, oa[ctl][it]);
    }
  }
#pragma unroll
  for (int ctl = 0; ctl < 4; ctl++)
#pragma unroll
    for (int it = 0; it < 4; it++) {
      int c = w * 64 + ctl * 16 + l15;
      size_t base = ((size_t)(b * C_ + c)) * N_ + i0 + it * 16 + quad * 4;
      f32x4 xs = *(const f32x4*)(x + base);
      float boc = bo[c];
      f32x4 o4;
#pragma unroll
      for (int r = 0; r < 4; r++) o4[r] = oa[ctl][it][r] + boc + xs[r];
      *(f32x4*)(out + base) = o4;     // coalesced 16B fp32 store, skip fused
    }
}

// ---------------------------------------------------------------- launch
extern "C" void kernel_launch(void* const* d_in, const int* in_sizes, int n_in,
                              void* d_out, int out_size, void* d_ws, size_t ws_size,
                              hipStream_t stream) {
  const float* x   = (const float*)d_in[0];
  const float* gsc = (const float*)d_in[1];
  const float* gbi = (const float*)d_in[2];
  const float* wq  = (const float*)d_in[3];
  const float* bq  = (const float*)d_in[4];
  const float* wk  = (const float*)d_in[5];
  const float* bk  = (const float*)d_in[6];
  const float* wv  = (const float*)d_in[7];
  const float* bv  = (const float*)d_in[8];
  const float* wo  = (const float*)d_in[9];
  const float* bo  = (const float*)d_in[10];

  char* ws = (char*)d_ws;
  bf16* hT  = (bf16*)(ws + HT_OFF);
  bf16* qT  = (bf16*)(ws + QT_OFF);
  bf16* kT  = (bf16*)(ws + KT_OFF);
  bf16* vv  = (bf16*)(ws + V_OFF);
  bf16* wqb = (bf16*)(ws + WQ_OFF);
  bf16* wkb = (bf16*)(ws + WK_OFF);
  bf16* wvb = (bf16*)(ws + WV_OFF);
  bf16* wob = (bf16*)(ws + WO_OFF);

  wconv_kernel<<<256, 256, 0, stream>>>(wq, wk, wv, wo, wqb, wkb, wvb, wob);
  gn_kernel<<<256, 256, 0, stream>>>(x, gsc, gbi, hT);
  qkv_kernel<<<512, 256, 0, stream>>>(hT, wqb, wkb, wvb, bq, bk, bv, qT, kT, vv);
  attn_kernel<<<512, 256, 0, stream>>>(qT, kT, vv, wob, bo, x, (float*)d_out);
}